// Round 4
// baseline (141.225 us; speedup 1.0000x reference)
//
#include <hip/hip_runtime.h>
#include <math.h>

typedef __attribute__((ext_vector_type(8))) short short8;
typedef __attribute__((ext_vector_type(4))) float f32x4;
typedef __attribute__((ext_vector_type(2))) float f32x2;

#define DEV static __device__ __forceinline__

DEV unsigned short f2b(float f){            // fp32 -> bf16 (RNE)
  union{float f; unsigned u;} x; x.f = f;
  unsigned r = (x.u + 0x7fffu + ((x.u>>16)&1u))>>16;
  return (unsigned short)r;
}

#define MFMA(a,b,c) __builtin_amdgcn_mfma_f32_16x16x32_bf16((a),(b),(c),0,0,0)

// ---------------------------------------------------------------------------
// Shared weight-prep logic: id in [0, 94560) converts weights to bf16 MFMA
// B-frag order (with LN-affine folding); [94208,94496) folds qkv biases;
// [94496,94560) folds mlp b1.
// ---------------------------------------------------------------------------
DEV void prep_one(int id,
    const float* inW, const float* Wq, const float* Wk, const float* Wv,
    const float* m1, const float* m2,
    const float* p1, const float* p2, const float* p3, const float* p4,
    const float* mss, const float* mls, const float* msb,
    const float* bq, const float* bk, const float* bv,
    const float* mlb, const float* mb1,
    unsigned short* wsw, float* qkvb, float* mlpb1)
{
  if(id < 94208){
    const float* src; int NT, base; int harg = -1, w1flag = 0;
    if      (id < 49152){ src=inW; NT=4; base=0; }
    else if (id < 67584){ int r=id-49152; int slab=r>>11; int h=slab/3, m=slab-h*3;
                          src=(m==0?Wq:(m==1?Wk:Wv))+h*2048; NT=2; base=49152+slab*2048; harg=h; }
    else if (id < 73728){ src=m1; NT=4; base=67584; }
    else if (id < 77824){ src=m2; NT=4; base=73728; }
    else if (id < 81920){ src=p1; NT=4; base=77824; w1flag=1; }
    else if (id < 86016){ src=p2; NT=4; base=81920; }
    else if (id < 90112){ src=p3; NT=4; base=86016; }
    else                { src=p4; NT=4; base=90112; }
    int o = id - base;
    int j = o&7, l = (o>>3)&63, rest = o>>9;
    int nt = rest % NT, kc = rest / NT;
    int k = kc*32 + ((l>>4)<<3) + j;
    int n = nt*16 + (l&15);
    float scale = 1.f;
    if(harg >= 0) scale = mss[harg*64 + k];
    if(w1flag)    scale = mls[k];
    wsw[id] = f2b(src[k*(NT*16) + n] * scale);
  } else if(id < 94496){
    int o = id - 94208;                     // 288: h*96 + m*32 + e
    int h = o/96, m = (o - h*96)/32, e = o&31;
    const float* W  = (m==0?Wq:(m==1?Wk:Wv)) + h*2048;
    const float* bb = (m==0?bq:(m==1?bk:bv));
    float s = 0.f;
    for(int l=0;l<64;++l) s += msb[h*64+l]*W[l*32+e];
    qkvb[o] = s + bb[h*32+e];
  } else if(id < 94560){
    int n = id - 94496;
    float s = 0.f;
    for(int l=0;l<64;++l) s += mlb[l]*p1[l*64+n];
    mlpb1[n] = s + mb1[n];
  }
}

// kprep: only the in_W frags (needed by k1). 192 blocks.
__global__ __launch_bounds__(256) void kprep(
    const float* __restrict__ inW, unsigned short* __restrict__ wsw)
{
  int id = blockIdx.x*256 + threadIdx.x;   // < 49152
  int o = id;
  int j = o&7, l = (o>>3)&63, rest = o>>9;
  int nt = rest & 3, kc = rest >> 2;
  int k = kc*32 + ((l>>4)<<3) + j;
  int n = nt*16 + (l&15);
  wsw[id] = f2b(inW[k*64 + n]);
}

// ---------------------------------------------------------------------------
// k1: blocks <4096: patchify + LN(768) + GEMM(768->64) + bias + LN(64)
//     -> xskip + per-row (mean,rstd). Blocks >=4096: rest of weight prep.
// ---------------------------------------------------------------------------
__global__ __launch_bounds__(256) void k1_patch(
    const float* __restrict__ x,
    const float* __restrict__ ln1s, const float* __restrict__ ln1b,
    unsigned short* __restrict__ wsw, const float* __restrict__ inb,
    const float* __restrict__ ln2s, const float* __restrict__ ln2b,
    float* __restrict__ xskip, float* __restrict__ rowstats,
    const float* __restrict__ inW,
    const float* __restrict__ Wq, const float* __restrict__ Wk,
    const float* __restrict__ Wv,
    const float* __restrict__ m1, const float* __restrict__ m2,
    const float* __restrict__ p1, const float* __restrict__ p2,
    const float* __restrict__ p3, const float* __restrict__ p4,
    const float* __restrict__ mss, const float* __restrict__ mls,
    const float* __restrict__ msb,
    const float* __restrict__ bq, const float* __restrict__ bk,
    const float* __restrict__ bv,
    const float* __restrict__ mlb, const float* __restrict__ mb1,
    float* __restrict__ qkvb, float* __restrict__ mlpb1)
{
  const int tid = threadIdx.x;
  const int bp = blockIdx.x;
  if(bp >= 4096){   // weight-prep tail (hides under main blocks' HBM streaming)
    int id = 49152 + (bp - 4096)*256 + tid;
    prep_one(id, inW, Wq, Wk, Wv, m1, m2, p1, p2, p3, p4,
             mss, mls, msb, bq, bk, bv, mlb, mb1, wsw, qkvb, mlpb1);
    return;
  }
  __shared__ unsigned short Tf[24*64*8];
  __shared__ float Cbuf[16][68];
  __shared__ float wstat[4][16][2];
  const int lane = tid & 63, wv = tid >> 6;
  const int p1i = tid & 15, jj = tid >> 4;
  const int b = bp >> 4, p0 = bp & 15;

  const float* xb = x + (size_t)b * (3*256*256);
  float rv[48]; float sum=0.f, ssq=0.f;
#pragma unroll
  for(int rr=0; rr<48; ++rr){
    int c = rr >> 4, i = rr & 15;
    float v = xb[(c*256 + i*16 + p0)*256 + tid];
    rv[rr] = v; sum += v; ssq += v*v;
  }
  sum += __shfl_xor(sum, 16); sum += __shfl_xor(sum, 32);
  ssq += __shfl_xor(ssq, 16); ssq += __shfl_xor(ssq, 32);
  if(lane < 16){ wstat[wv][lane][0] = sum; wstat[wv][lane][1] = ssq; }
  __syncthreads();
  float ts = wstat[0][p1i][0] + wstat[1][p1i][0] + wstat[2][p1i][0] + wstat[3][p1i][0];
  float tq = wstat[0][p1i][1] + wstat[1][p1i][1] + wstat[2][p1i][1] + wstat[3][p1i][1];
  float mean = ts * (1.f/768.f);
  float var  = tq * (1.f/768.f) - mean*mean;
  float rstd = rsqrtf(var + 1e-5f);
#pragma unroll
  for(int rr=0; rr<48; ++rr){
    int c = rr >> 4, i = rr & 15;
    int d = c*256 + i*16 + jj;
    float xv = (rv[rr]-mean)*rstd*ln1s[d] + ln1b[d];
    int g = (((i&1)<<4) + jj) >> 3;
    Tf[ (((d>>5)*64 + g*16 + p1i)<<3) + (jj&7) ] = f2b(xv);
  }
  __syncthreads();

  f32x4 acc = {0.f,0.f,0.f,0.f};
  const short8* wf = (const short8*)wsw;
#pragma unroll
  for(int kc=0; kc<24; ++kc){
    short8 a  = *(const short8*)&Tf[(kc*64 + lane)*8];
    short8 bb = wf[(kc*4 + wv)*64 + lane];
    acc = MFMA(a, bb, acc);
  }
  const int c15 = lane & 15, rg = lane >> 4;
  float bias = inb[wv*16 + c15];
#pragma unroll
  for(int r=0; r<4; ++r) Cbuf[rg*4+r][wv*16+c15] = acc[r] + bias;
  __syncthreads();

  {
    int row = tid >> 4, cq = (tid & 15) * 4;
    float v0=Cbuf[row][cq+0], v1=Cbuf[row][cq+1], v2=Cbuf[row][cq+2], v3=Cbuf[row][cq+3];
    float s = v0+v1+v2+v3;
    float q = v0*v0+v1*v1+v2*v2+v3*v3;
    s += __shfl_xor(s,1); s += __shfl_xor(s,2); s += __shfl_xor(s,4); s += __shfl_xor(s,8);
    q += __shfl_xor(q,1); q += __shfl_xor(q,2); q += __shfl_xor(q,4); q += __shfl_xor(q,8);
    float m2  = s*(1.f/64.f);
    float rs2 = rsqrtf(q*(1.f/64.f) - m2*m2 + 1e-5f);
    f32x4 o;
    o[0] = (v0-m2)*rs2*ln2s[cq+0] + ln2b[cq+0];
    o[1] = (v1-m2)*rs2*ln2s[cq+1] + ln2b[cq+1];
    o[2] = (v2-m2)*rs2*ln2s[cq+2] + ln2b[cq+2];
    o[3] = (v3-m2)*rs2*ln2s[cq+3] + ln2b[cq+3];
    int grow = b*256 + p0*16 + row;
    *(f32x4*)&xskip[ (size_t)grow*64 + cq ] = o;
    float s2 = o[0]+o[1]+o[2]+o[3];
    float q2 = o[0]*o[0]+o[1]*o[1]+o[2]*o[2]+o[3]*o[3];
    s2 += __shfl_xor(s2,1); s2 += __shfl_xor(s2,2); s2 += __shfl_xor(s2,4); s2 += __shfl_xor(s2,8);
    q2 += __shfl_xor(q2,1); q2 += __shfl_xor(q2,2); q2 += __shfl_xor(q2,4); q2 += __shfl_xor(q2,8);
    if((tid & 15) == 0){
      float mm = s2*(1.f/64.f);
      float rr2 = rsqrtf(q2*(1.f/64.f) - mm*mm + 1e-5f);
      f32x2 st; st[0] = mm; st[1] = rr2;
      *(f32x2*)&rowstats[grow*2] = st;
    }
  }
}

// ---------------------------------------------------------------------------
// kA: fused attention per (b,h), LDS-diet version (40 KB -> 4 blocks/CU).
// z A-frags loaded straight from global into registers (no z LDS/barrier);
// Q staged through per-wave 2KB scratch; K,V in shared LDS (verified layouts);
// P staged per-kc through the same per-wave scratch with interleaved PV.
// ---------------------------------------------------------------------------
__global__ __launch_bounds__(256) void kA_attn(
    const float* __restrict__ xskip, const float* __restrict__ rowstats,
    const unsigned short* __restrict__ wsw, const float* __restrict__ qkvb,
    unsigned short* __restrict__ cat)
{
  __shared__ unsigned short Kf[8192];      // 16 KB
  __shared__ unsigned short Vf[8192];      // 16 KB
  __shared__ unsigned short scr[4][1024];  //  8 KB (per-wave 2 KB)
  const int tid = threadIdx.x, lane = tid&63, wv = tid>>6;
  const int c15 = lane&15, rg = lane>>4;
  const int id = blockIdx.x, b = id/3, h = id - b*3;
  const float* xr = xskip + (size_t)b*16384;
  const float* rs = rowstats + (size_t)b*512;
  const short8* wf = ((const short8*)(wsw + 49152)) + h*3*256;
  unsigned short* sw = scr[wv];
  float be[6];
#pragma unroll
  for(int i=0;i<6;++i) be[i] = qkvb[(h*3 + (i>>1))*32 + (i&1)*16 + c15];

  short8 aq[4];                            // Q A-frags, one per st
#pragma unroll
  for(int si=0; si<4; ++si){
    const int st = wv + si*4;
    // z A-frags in registers: elem(kc,l,j) = z[st*16+(l&15)][kc*32+(l>>4)*8+j]
    short8 a0, a1;
    {
      int row = st*16 + c15;
      f32x2 stt = *(const f32x2*)&rs[row*2];
      const float* rp = &xr[row*64 + rg*8];
      f32x4 u0 = *(const f32x4*)&rp[0];
      f32x4 u1 = *(const f32x4*)&rp[4];
      f32x4 u2 = *(const f32x4*)&rp[32];
      f32x4 u3 = *(const f32x4*)&rp[36];
#pragma unroll
      for(int j=0;j<4;++j){
        a0[j]   = (short)f2b((u0[j]-stt[0])*stt[1]);
        a0[4+j] = (short)f2b((u1[j]-stt[0])*stt[1]);
        a1[j]   = (short)f2b((u2[j]-stt[0])*stt[1]);
        a1[4+j] = (short)f2b((u3[j]-stt[0])*stt[1]);
      }
    }
#pragma unroll
    for(int mat=0; mat<3; ++mat){
#pragma unroll
      for(int et=0; et<2; ++et){
        f32x4 acc = {0.f,0.f,0.f,0.f};
        acc = MFMA(a0, wf[mat*256 + et*64 + lane], acc);
        acc = MFMA(a1, wf[mat*256 + (2+et)*64 + lane], acc);
        float bias = be[mat*2+et];
#pragma unroll
        for(int r=0;r<4;++r){
          unsigned short val = f2b(acc[r] + bias);
          int s15 = rg*4 + r;
          if(mat==0){
            sw[ ((et*2 + (c15>>3))*16 + s15)*8 + (c15&7) ] = val;
          } else if(mat==1){
            Kf[ (st*64 + (et*2 + (c15>>3))*16 + s15)*8 + (c15&7) ] = val;
          } else {
            int s = st*16 + s15;
            Vf[ (((s>>5)*2 + et)*64 + ((s&31)>>3)*16 + c15)*8 + (s&7) ] = val;
          }
        }
      }
      if(mat==0) aq[si] = ((const short8*)sw)[lane];   // wave-local readback
    }
  }
  __syncthreads();

  const f32x4 z4 = {0.f,0.f,0.f,0.f};
#pragma unroll
  for(int si=0; si<4; ++si){
    const int st = wv + si*4;
    f32x4 sc[16];
#pragma unroll
    for(int tt=0; tt<16; ++tt) sc[tt] = MFMA(aq[si], ((const short8*)Kf)[tt*64 + lane], z4);
    float mx[4], sm[4];
#pragma unroll
    for(int r=0; r<4; ++r){
      float m = sc[0][r];
#pragma unroll
      for(int tt=1; tt<16; ++tt) m = fmaxf(m, sc[tt][r]);
      m = fmaxf(m, __shfl_xor(m,1)); m = fmaxf(m, __shfl_xor(m,2));
      m = fmaxf(m, __shfl_xor(m,4)); m = fmaxf(m, __shfl_xor(m,8));
      mx[r] = m; sm[r] = 0.f;
    }
#pragma unroll
    for(int tt=0; tt<16; ++tt)
#pragma unroll
      for(int r=0; r<4; ++r){
        float e = __expf(sc[tt][r] - mx[r]);
        sc[tt][r] = e; sm[r] += e;
      }
#pragma unroll
    for(int r=0; r<4; ++r){
      float s = sm[r];
      s += __shfl_xor(s,1); s += __shfl_xor(s,2); s += __shfl_xor(s,4); s += __shfl_xor(s,8);
      sm[r] = 1.f / s;
    }
    f32x4 o0 = z4, o1 = z4;
#pragma unroll
    for(int kc=0; kc<8; ++kc){
#pragma unroll
      for(int t2=0; t2<2; ++t2){
        int tt = kc*2 + t2;
        int tbr = t2*16 + c15;       // tb & 31
#pragma unroll
        for(int r=0; r<4; ++r)
          sw[ (((tbr>>3)*16 + rg*4 + r)<<3) + (tbr&7) ] = f2b(sc[tt][r] * sm[r]);
      }
      short8 pa = ((const short8*)sw)[lane];
      o0 = MFMA(pa, ((const short8*)Vf)[(kc*2+0)*64 + lane], o0);
      o1 = MFMA(pa, ((const short8*)Vf)[(kc*2+1)*64 + lane], o1);
    }
#pragma unroll
    for(int r=0; r<4; ++r){
      size_t co = (size_t)(b*256 + st*16 + rg*4 + r)*96 + h*32;
      cat[co + c15]      = f2b(o0[r]);
      cat[co + 16 + c15] = f2b(o1[r]);
    }
  }
}

// ---------------------------------------------------------------------------
// kB: fused tail per b (grid 256): loop over 4 row-groups; mhp 2-GEMM +
// residual (registers), LN stats, mlp 4-GEMM chain, residual, out_W dot;
// writes out[b] directly (k5 merged).
// ---------------------------------------------------------------------------
__global__ __launch_bounds__(256) void kB_tail(
    const unsigned short* __restrict__ cat, const float* __restrict__ xskip,
    const unsigned short* __restrict__ w1f, const float* __restrict__ b1,
    const unsigned short* __restrict__ w2f, const float* __restrict__ b2,
    const unsigned short* __restrict__ p1f, const float* __restrict__ p1b,
    const unsigned short* __restrict__ p2f, const float* __restrict__ pb2,
    const unsigned short* __restrict__ p3f, const float* __restrict__ pb3,
    const unsigned short* __restrict__ p4f, const float* __restrict__ pb4,
    const float* __restrict__ outw, const float* __restrict__ outb,
    float* __restrict__ out)
{
  __shared__ unsigned short catf[6144];
  __shared__ unsigned short fa[4096];
  __shared__ unsigned short fb[4096];
  __shared__ float rstat[4][64][2];
  __shared__ float red[4];
  const int tid = threadIdx.x, lane = tid&63, wv = tid>>6;
  const int c15 = lane&15, rg = lane>>4;
  const int b = blockIdx.x;
  const short8* w1 = (const short8*)w1f;
  const short8* w2 = (const short8*)w2f;
  const short8* q1 = (const short8*)p1f;
  const short8* q2 = (const short8*)p2f;
  const short8* q3 = (const short8*)p3f;
  const short8* q4 = (const short8*)p4f;
  const int kch = wv>>1, gw = (wv&1)*2 + (c15>>3), jw = c15&7;
  float bsum = 0.f;

  for(int sg=0; sg<4; ++sg){
    const unsigned short* cb = cat + (size_t)(b*256 + sg*64)*96;
#pragma unroll
    for(int it=0; it<24; ++it){
      int flat = it*256 + tid;
      int row = flat/96, col = flat - row*96;
      catf[ ((((row>>4)*3 + (col>>5))*64 + ((col&31)>>3)*16 + (row&15))<<3) + (col&7) ] = cb[flat];
    }
    __syncthreads();
    {  // mhp G1 -> fa
      float bb = b1[wv*16+c15];
#pragma unroll
      for(int st=0; st<4; ++st){
        f32x4 a = {0.f,0.f,0.f,0.f};
#pragma unroll
        for(int kc=0; kc<3; ++kc)
          a = MFMA(*(const short8*)&catf[((st*3+kc)*64+lane)*8], w1[(kc*4+wv)*64+lane], a);
#pragma unroll
        for(int r=0; r<4; ++r)
          fa[ (((st*2+kch)*64 + gw*16 + rg*4 + r)<<3) + jw ] = f2b(a[r] + bb);
      }
    }
    __syncthreads();
    f32x4 xs2[4];
    const float* xr = xskip + (size_t)(b*256 + sg*64)*64;
    {  // mhp G2 + residual -> xs2 regs
      float bb = b2[wv*16+c15];
#pragma unroll
      for(int st=0; st<4; ++st){
        f32x4 a = {0.f,0.f,0.f,0.f};
#pragma unroll
        for(int kc=0; kc<2; ++kc)
          a = MFMA(*(const short8*)&fa[((st*2+kc)*64+lane)*8], w2[(kc*4+wv)*64+lane], a);
#pragma unroll
        for(int r=0; r<4; ++r)
          xs2[st][r] = a[r] + bb + xr[(st*16 + rg*4 + r)*64 + wv*16 + c15];
      }
    }
#pragma unroll
    for(int st=0; st<4; ++st)
#pragma unroll
      for(int r=0; r<4; ++r){
        float sv = xs2[st][r], qv = sv*sv;
        sv += __shfl_xor(sv,1); sv += __shfl_xor(sv,2); sv += __shfl_xor(sv,4); sv += __shfl_xor(sv,8);
        qv += __shfl_xor(qv,1); qv += __shfl_xor(qv,2); qv += __shfl_xor(qv,4); qv += __shfl_xor(qv,8);
        if(c15==0){ int row = st*16+rg*4+r; rstat[wv][row][0]=sv; rstat[wv][row][1]=qv; }
      }
    __syncthreads();
#pragma unroll
    for(int st=0; st<4; ++st)
#pragma unroll
      for(int r=0; r<4; ++r){
        int row = st*16+rg*4+r;
        float tsu = rstat[0][row][0]+rstat[1][row][0]+rstat[2][row][0]+rstat[3][row][0];
        float tqu = rstat[0][row][1]+rstat[1][row][1]+rstat[2][row][1]+rstat[3][row][1];
        float mean = tsu*(1.f/64.f);
        float rstd = rsqrtf(tqu*(1.f/64.f) - mean*mean + 1e-5f);
        fa[ (((st*2+kch)*64 + gw*16 + (row&15))<<3) + jw ] = f2b((xs2[st][r]-mean)*rstd);
      }
    __syncthreads();
    {  // mlp G1 (folded) -> fb
      float bb = p1b[wv*16+c15];
#pragma unroll
      for(int st=0; st<4; ++st){
        f32x4 a = {0.f,0.f,0.f,0.f};
#pragma unroll
        for(int kc=0; kc<2; ++kc)
          a = MFMA(*(const short8*)&fa[((st*2+kc)*64+lane)*8], q1[(kc*4+wv)*64+lane], a);
#pragma unroll
        for(int r=0; r<4; ++r)
          fb[ (((st*2+kch)*64 + gw*16 + rg*4 + r)<<3) + jw ] = f2b(a[r] + bb);
      }
    }
    __syncthreads();
    {  // mlp G2 + exact gelu -> fa
      float bb = pb2[wv*16+c15];
#pragma unroll
      for(int st=0; st<4; ++st){
        f32x4 a = {0.f,0.f,0.f,0.f};
#pragma unroll
        for(int kc=0; kc<2; ++kc)
          a = MFMA(*(const short8*)&fb[((st*2+kc)*64+lane)*8], q2[(kc*4+wv)*64+lane], a);
#pragma unroll
        for(int r=0; r<4; ++r){
          float v = a[r] + bb;
          v = 0.5f*v*(1.f + erff(v*0.70710678118654752440f));
          fa[ (((st*2+kch)*64 + gw*16 + rg*4 + r)<<3) + jw ] = f2b(v);
        }
      }
    }
    __syncthreads();
    {  // mlp G3 -> fb
      float bb = pb3[wv*16+c15];
#pragma unroll
      for(int st=0; st<4; ++st){
        f32x4 a = {0.f,0.f,0.f,0.f};
#pragma unroll
        for(int kc=0; kc<2; ++kc)
          a = MFMA(*(const short8*)&fa[((st*2+kc)*64+lane)*8], q3[(kc*4+wv)*64+lane], a);
#pragma unroll
        for(int r=0; r<4; ++r)
          fb[ (((st*2+kch)*64 + gw*16 + rg*4 + r)<<3) + jw ] = f2b(a[r] + bb);
      }
    }
    __syncthreads();
    {  // mlp G4 + residual + out_W dot
      float bb = pb4[wv*16+c15];
#pragma unroll
      for(int st=0; st<4; ++st){
        f32x4 a = {0.f,0.f,0.f,0.f};
#pragma unroll
        for(int kc=0; kc<2; ++kc)
          a = MFMA(*(const short8*)&fb[((st*2+kc)*64+lane)*8], q4[(kc*4+wv)*64+lane], a);
#pragma unroll
        for(int r=0; r<4; ++r){
          int row = st*16 + rg*4 + r;
          float v = a[r] + bb + xs2[st][r];
          bsum += v * outw[(sg*64 + row)*64 + wv*16 + c15];
        }
      }
    }
    __syncthreads();   // protect catf/fa/fb reuse next sg
  }
  bsum += __shfl_xor(bsum,1); bsum += __shfl_xor(bsum,2);
  bsum += __shfl_xor(bsum,4); bsum += __shfl_xor(bsum,8);
  bsum += __shfl_xor(bsum,16); bsum += __shfl_xor(bsum,32);
  if(lane==0) red[wv] = bsum;
  __syncthreads();
  if(tid==0) out[b] = red[0]+red[1]+red[2]+red[3] + outb[0];
}

// ---------------------------------------------------------------------------
extern "C" void kernel_launch(void* const* d_in, const int* in_sizes, int n_in,
                              void* d_out, int out_size, void* d_ws, size_t ws_size,
                              hipStream_t stream)
{
  const float* x    = (const float*)d_in[0];
  const float* ln1s = (const float*)d_in[1];
  const float* ln1b = (const float*)d_in[2];
  const float* inW  = (const float*)d_in[3];
  const float* inb  = (const float*)d_in[4];
  const float* ln2s = (const float*)d_in[5];
  const float* ln2b = (const float*)d_in[6];
  const float* mss  = (const float*)d_in[7];
  const float* msb  = (const float*)d_in[8];
  const float* Wq   = (const float*)d_in[9];
  const float* bq   = (const float*)d_in[10];
  const float* Wk   = (const float*)d_in[11];
  const float* bk   = (const float*)d_in[12];
  const float* Wv   = (const float*)d_in[13];
  const float* bv   = (const float*)d_in[14];
  const float* mhW1 = (const float*)d_in[15];
  const float* mhb1 = (const float*)d_in[16];
  const float* mhW2 = (const float*)d_in[17];
  const float* mhb2 = (const float*)d_in[18];
  const float* mls  = (const float*)d_in[19];
  const float* mlb  = (const float*)d_in[20];
  const float* mW1  = (const float*)d_in[21];
  const float* mb1  = (const float*)d_in[22];
  const float* mW2  = (const float*)d_in[23];
  const float* mb2  = (const float*)d_in[24];
  const float* mW3  = (const float*)d_in[25];
  const float* mb3  = (const float*)d_in[26];
  const float* mW4  = (const float*)d_in[27];
  const float* mb4  = (const float*)d_in[28];
  const float* outW = (const float*)d_in[29];
  const float* outb = (const float*)d_in[30];
  (void)in_sizes; (void)n_in; (void)out_size;

  // workspace layout (bytes)
  char* ws = (char*)d_ws;
  float*          xskip    = (float*)         (ws + 0);          // 16,777,216
  unsigned short* cat      = (unsigned short*)(ws + 16777216);   // 12,582,912
  unsigned short* wsw      = (unsigned short*)(ws + 29360128);   //    188,416
  float*          rowstats = (float*)         (ws + 29548544);   //    524,288
  float*          qkvb     = (float*)         (ws + 30072832);   //      1,152
  float*          mlpb1    = (float*)         (ws + 30073984);   //        256
  if(ws_size < 30074240u) return;

  float* out = (float*)d_out;

  kprep<<<dim3(192), dim3(256), 0, stream>>>(inW, wsw);
  k1_patch<<<dim3(4096 + 178), dim3(256), 0, stream>>>(x, ln1s, ln1b, wsw, inb,
      ln2s, ln2b, xskip, rowstats,
      inW, Wq, Wk, Wv, mhW1, mhW2, mW1, mW2, mW3, mW4,
      mss, mls, msb, bq, bk, bv, mlb, mb1, qkvb, mlpb1);
  kA_attn<<<dim3(768), dim3(256), 0, stream>>>(xskip, rowstats, wsw, qkvb, cat);
  kB_tail<<<dim3(256), dim3(256), 0, stream>>>(cat, xskip,
      wsw + 67584, mhb1, wsw + 73728, mhb2,
      wsw + 77824, mlpb1, wsw + 81920, mb2, wsw + 86016, mb3, wsw + 90112, mb4,
      outW, outb, out);
}

// Round 5
// 127.207 us; speedup vs baseline: 1.1102x; 1.1102x over previous
//
#include <hip/hip_runtime.h>
#include <math.h>

typedef __attribute__((ext_vector_type(8))) short short8;
typedef __attribute__((ext_vector_type(4))) float f32x4;
typedef __attribute__((ext_vector_type(2))) float f32x2;

#define DEV static __device__ __forceinline__

DEV unsigned short f2b(float f){            // fp32 -> bf16 (RNE)
  union{float f; unsigned u;} x; x.f = f;
  unsigned r = (x.u + 0x7fffu + ((x.u>>16)&1u))>>16;
  return (unsigned short)r;
}

#define MFMA(a,b,c) __builtin_amdgcn_mfma_f32_16x16x32_bf16((a),(b),(c),0,0,0)

// ---------------------------------------------------------------------------
// Weight-prep: ids [0,94208) -> bf16 B-frag order (LN-affine folded);
// [94208,94496) qkv bias folds; [94496,94560) mlp b1 fold.
// ---------------------------------------------------------------------------
DEV void prep_one(int id,
    const float* inW, const float* Wq, const float* Wk, const float* Wv,
    const float* m1, const float* m2,
    const float* p1, const float* p2, const float* p3, const float* p4,
    const float* mss, const float* mls, const float* msb,
    const float* bq, const float* bk, const float* bv,
    const float* mlb, const float* mb1,
    unsigned short* wsw, float* qkvb, float* mlpb1)
{
  if(id < 94208){
    const float* src; int NT, base; int harg = -1, w1flag = 0;
    if      (id < 49152){ src=inW; NT=4; base=0; }
    else if (id < 67584){ int r=id-49152; int slab=r>>11; int h=slab/3, m=slab-h*3;
                          src=(m==0?Wq:(m==1?Wk:Wv))+h*2048; NT=2; base=49152+slab*2048; harg=h; }
    else if (id < 73728){ src=m1; NT=4; base=67584; }
    else if (id < 77824){ src=m2; NT=4; base=73728; }
    else if (id < 81920){ src=p1; NT=4; base=77824; w1flag=1; }
    else if (id < 86016){ src=p2; NT=4; base=81920; }
    else if (id < 90112){ src=p3; NT=4; base=86016; }
    else                { src=p4; NT=4; base=90112; }
    int o = id - base;
    int j = o&7, l = (o>>3)&63, rest = o>>9;
    int nt = rest % NT, kc = rest / NT;
    int k = kc*32 + ((l>>4)<<3) + j;
    int n = nt*16 + (l&15);
    float scale = 1.f;
    if(harg >= 0) scale = mss[harg*64 + k];
    if(w1flag)    scale = mls[k];
    wsw[id] = f2b(src[k*(NT*16) + n] * scale);
  } else if(id < 94496){
    int o = id - 94208;                     // 288: h*96 + m*32 + e
    int h = o/96, m = (o - h*96)/32, e = o&31;
    const float* W  = (m==0?Wq:(m==1?Wk:Wv)) + h*2048;
    const float* bb = (m==0?bq:(m==1?bk:bv));
    float s = 0.f;
    for(int l=0;l<64;++l) s += msb[h*64+l]*W[l*32+e];
    qkvb[o] = s + bb[h*32+e];
  } else if(id < 94560){
    int n = id - 94496;
    float s = 0.f;
    for(int l=0;l<64;++l) s += mlb[l]*p1[l*64+n];
    mlpb1[n] = s + mb1[n];
  }
}

// kprep: only the in_W frags (needed by k1). 192 blocks.
__global__ __launch_bounds__(256) void kprep(
    const float* __restrict__ inW, unsigned short* __restrict__ wsw)
{
  int id = blockIdx.x*256 + threadIdx.x;   // < 49152
  int o = id;
  int j = o&7, l = (o>>3)&63, rest = o>>9;
  int nt = rest & 3, kc = rest >> 2;
  int k = kc*32 + ((l>>4)<<3) + j;
  int n = nt*16 + (l&15);
  wsw[id] = f2b(inW[k*64 + n]);
}

// ---------------------------------------------------------------------------
// k1: blocks <4096: patchify + LN(768) + GEMM(768->64) + bias + LN(64)
//     -> xskip + per-row (mean,rstd). Blocks >=4096: rest of weight prep
//     (hides under the main blocks' HBM streaming).
// ---------------------------------------------------------------------------
__global__ __launch_bounds__(256) void k1_patch(
    const float* __restrict__ x,
    const float* __restrict__ ln1s, const float* __restrict__ ln1b,
    unsigned short* __restrict__ wsw, const float* __restrict__ inb,
    const float* __restrict__ ln2s, const float* __restrict__ ln2b,
    float* __restrict__ xskip, float* __restrict__ rowstats,
    const float* __restrict__ inW,
    const float* __restrict__ Wq, const float* __restrict__ Wk,
    const float* __restrict__ Wv,
    const float* __restrict__ m1, const float* __restrict__ m2,
    const float* __restrict__ p1, const float* __restrict__ p2,
    const float* __restrict__ p3, const float* __restrict__ p4,
    const float* __restrict__ mss, const float* __restrict__ mls,
    const float* __restrict__ msb,
    const float* __restrict__ bq, const float* __restrict__ bk,
    const float* __restrict__ bv,
    const float* __restrict__ mlb, const float* __restrict__ mb1,
    float* __restrict__ qkvb, float* __restrict__ mlpb1)
{
  const int tid = threadIdx.x;
  const int bp = blockIdx.x;
  if(bp >= 4096){
    int id = 49152 + (bp - 4096)*256 + tid;
    prep_one(id, inW, Wq, Wk, Wv, m1, m2, p1, p2, p3, p4,
             mss, mls, msb, bq, bk, bv, mlb, mb1, wsw, qkvb, mlpb1);
    return;
  }
  __shared__ unsigned short Tf[24*64*8];
  __shared__ float Cbuf[16][68];
  __shared__ float wstat[4][16][2];
  const int lane = tid & 63, wv = tid >> 6;
  const int p1i = tid & 15, jj = tid >> 4;
  const int b = bp >> 4, p0 = bp & 15;

  const float* xb = x + (size_t)b * (3*256*256);
  float rv[48]; float sum=0.f, ssq=0.f;
#pragma unroll
  for(int rr=0; rr<48; ++rr){
    int c = rr >> 4, i = rr & 15;
    float v = xb[(c*256 + i*16 + p0)*256 + tid];
    rv[rr] = v; sum += v; ssq += v*v;
  }
  sum += __shfl_xor(sum, 16); sum += __shfl_xor(sum, 32);
  ssq += __shfl_xor(ssq, 16); ssq += __shfl_xor(ssq, 32);
  if(lane < 16){ wstat[wv][lane][0] = sum; wstat[wv][lane][1] = ssq; }
  __syncthreads();
  float ts = wstat[0][p1i][0] + wstat[1][p1i][0] + wstat[2][p1i][0] + wstat[3][p1i][0];
  float tq = wstat[0][p1i][1] + wstat[1][p1i][1] + wstat[2][p1i][1] + wstat[3][p1i][1];
  float mean = ts * (1.f/768.f);
  float var  = tq * (1.f/768.f) - mean*mean;
  float rstd = rsqrtf(var + 1e-5f);
#pragma unroll
  for(int rr=0; rr<48; ++rr){
    int c = rr >> 4, i = rr & 15;
    int d = c*256 + i*16 + jj;
    float xv = (rv[rr]-mean)*rstd*ln1s[d] + ln1b[d];
    int g = (((i&1)<<4) + jj) >> 3;
    Tf[ (((d>>5)*64 + g*16 + p1i)<<3) + (jj&7) ] = f2b(xv);
  }
  __syncthreads();

  f32x4 acc = {0.f,0.f,0.f,0.f};
  const short8* wf = (const short8*)wsw;
#pragma unroll
  for(int kc=0; kc<24; ++kc){
    short8 a  = *(const short8*)&Tf[(kc*64 + lane)*8];
    short8 bb = wf[(kc*4 + wv)*64 + lane];
    acc = MFMA(a, bb, acc);
  }
  const int c15 = lane & 15, rg = lane >> 4;
  float bias = inb[wv*16 + c15];
#pragma unroll
  for(int r=0; r<4; ++r) Cbuf[rg*4+r][wv*16+c15] = acc[r] + bias;
  __syncthreads();

  {
    int row = tid >> 4, cq = (tid & 15) * 4;
    float v0=Cbuf[row][cq+0], v1=Cbuf[row][cq+1], v2=Cbuf[row][cq+2], v3=Cbuf[row][cq+3];
    float s = v0+v1+v2+v3;
    float q = v0*v0+v1*v1+v2*v2+v3*v3;
    s += __shfl_xor(s,1); s += __shfl_xor(s,2); s += __shfl_xor(s,4); s += __shfl_xor(s,8);
    q += __shfl_xor(q,1); q += __shfl_xor(q,2); q += __shfl_xor(q,4); q += __shfl_xor(q,8);
    float m2  = s*(1.f/64.f);
    float rs2 = rsqrtf(q*(1.f/64.f) - m2*m2 + 1e-5f);
    f32x4 o;
    o[0] = (v0-m2)*rs2*ln2s[cq+0] + ln2b[cq+0];
    o[1] = (v1-m2)*rs2*ln2s[cq+1] + ln2b[cq+1];
    o[2] = (v2-m2)*rs2*ln2s[cq+2] + ln2b[cq+2];
    o[3] = (v3-m2)*rs2*ln2s[cq+3] + ln2b[cq+3];
    int grow = b*256 + p0*16 + row;
    *(f32x4*)&xskip[ (size_t)grow*64 + cq ] = o;
    float s2 = o[0]+o[1]+o[2]+o[3];
    float q2 = o[0]*o[0]+o[1]*o[1]+o[2]*o[2]+o[3]*o[3];
    s2 += __shfl_xor(s2,1); s2 += __shfl_xor(s2,2); s2 += __shfl_xor(s2,4); s2 += __shfl_xor(s2,8);
    q2 += __shfl_xor(q2,1); q2 += __shfl_xor(q2,2); q2 += __shfl_xor(q2,4); q2 += __shfl_xor(q2,8);
    if((tid & 15) == 0){
      float mm = s2*(1.f/64.f);
      float rr2 = rsqrtf(q2*(1.f/64.f) - mm*mm + 1e-5f);
      f32x2 st; st[0] = mm; st[1] = rr2;
      *(f32x2*)&rowstats[grow*2] = st;
    }
  }
}

// ---------------------------------------------------------------------------
// kA: fused attention per (b,h), 40 KB LDS -> 4 blocks/CU, all 768 resident.
// z A-frags direct from global into registers; Q via per-wave scratch;
// K,V in shared LDS; P staged per-kc through per-wave scratch.
// ---------------------------------------------------------------------------
__global__ __launch_bounds__(256) void kA_attn(
    const float* __restrict__ xskip, const float* __restrict__ rowstats,
    const unsigned short* __restrict__ wsw, const float* __restrict__ qkvb,
    unsigned short* __restrict__ cat)
{
  __shared__ unsigned short Kf[8192];      // 16 KB
  __shared__ unsigned short Vf[8192];      // 16 KB
  __shared__ unsigned short scr[4][1024];  //  8 KB (per-wave 2 KB)
  const int tid = threadIdx.x, lane = tid&63, wv = tid>>6;
  const int c15 = lane&15, rg = lane>>4;
  const int id = blockIdx.x, b = id/3, h = id - b*3;
  const float* xr = xskip + (size_t)b*16384;
  const float* rs = rowstats + (size_t)b*512;
  const short8* wf = ((const short8*)(wsw + 49152)) + h*3*256;
  unsigned short* sw = scr[wv];
  float be[6];
#pragma unroll
  for(int i=0;i<6;++i) be[i] = qkvb[(h*3 + (i>>1))*32 + (i&1)*16 + c15];

  short8 aq[4];                            // Q A-frags, one per st
#pragma unroll
  for(int si=0; si<4; ++si){
    const int st = wv + si*4;
    short8 a0, a1;
    {
      int row = st*16 + c15;
      f32x2 stt = *(const f32x2*)&rs[row*2];
      const float* rp = &xr[row*64 + rg*8];
      f32x4 u0 = *(const f32x4*)&rp[0];
      f32x4 u1 = *(const f32x4*)&rp[4];
      f32x4 u2 = *(const f32x4*)&rp[32];
      f32x4 u3 = *(const f32x4*)&rp[36];
#pragma unroll
      for(int j=0;j<4;++j){
        a0[j]   = (short)f2b((u0[j]-stt[0])*stt[1]);
        a0[4+j] = (short)f2b((u1[j]-stt[0])*stt[1]);
        a1[j]   = (short)f2b((u2[j]-stt[0])*stt[1]);
        a1[4+j] = (short)f2b((u3[j]-stt[0])*stt[1]);
      }
    }
#pragma unroll
    for(int mat=0; mat<3; ++mat){
#pragma unroll
      for(int et=0; et<2; ++et){
        f32x4 acc = {0.f,0.f,0.f,0.f};
        acc = MFMA(a0, wf[mat*256 + et*64 + lane], acc);
        acc = MFMA(a1, wf[mat*256 + (2+et)*64 + lane], acc);
        float bias = be[mat*2+et];
#pragma unroll
        for(int r=0;r<4;++r){
          unsigned short val = f2b(acc[r] + bias);
          int s15 = rg*4 + r;
          if(mat==0){
            sw[ ((et*2 + (c15>>3))*16 + s15)*8 + (c15&7) ] = val;
          } else if(mat==1){
            Kf[ (st*64 + (et*2 + (c15>>3))*16 + s15)*8 + (c15&7) ] = val;
          } else {
            int s = st*16 + s15;
            Vf[ (((s>>5)*2 + et)*64 + ((s&31)>>3)*16 + c15)*8 + (s&7) ] = val;
          }
        }
      }
      if(mat==0) aq[si] = ((const short8*)sw)[lane];   // wave-local readback
    }
  }
  __syncthreads();

  const f32x4 z4 = {0.f,0.f,0.f,0.f};
#pragma unroll
  for(int si=0; si<4; ++si){
    const int st = wv + si*4;
    f32x4 sc[16];
#pragma unroll
    for(int tt=0; tt<16; ++tt) sc[tt] = MFMA(aq[si], ((const short8*)Kf)[tt*64 + lane], z4);
    float mx[4], sm[4];
#pragma unroll
    for(int r=0; r<4; ++r){
      float m = sc[0][r];
#pragma unroll
      for(int tt=1; tt<16; ++tt) m = fmaxf(m, sc[tt][r]);
      m = fmaxf(m, __shfl_xor(m,1)); m = fmaxf(m, __shfl_xor(m,2));
      m = fmaxf(m, __shfl_xor(m,4)); m = fmaxf(m, __shfl_xor(m,8));
      mx[r] = m; sm[r] = 0.f;
    }
#pragma unroll
    for(int tt=0; tt<16; ++tt)
#pragma unroll
      for(int r=0; r<4; ++r){
        float e = __expf(sc[tt][r] - mx[r]);
        sc[tt][r] = e; sm[r] += e;
      }
#pragma unroll
    for(int r=0; r<4; ++r){
      float s = sm[r];
      s += __shfl_xor(s,1); s += __shfl_xor(s,2); s += __shfl_xor(s,4); s += __shfl_xor(s,8);
      sm[r] = 1.f / s;
    }
    f32x4 o0 = z4, o1 = z4;
#pragma unroll
    for(int kc=0; kc<8; ++kc){
#pragma unroll
      for(int t2=0; t2<2; ++t2){
        int tt = kc*2 + t2;
        int tbr = t2*16 + c15;
#pragma unroll
        for(int r=0; r<4; ++r)
          sw[ (((tbr>>3)*16 + rg*4 + r)<<3) + (tbr&7) ] = f2b(sc[tt][r] * sm[r]);
      }
      short8 pa = ((const short8*)sw)[lane];
      o0 = MFMA(pa, ((const short8*)Vf)[(kc*2+0)*64 + lane], o0);
      o1 = MFMA(pa, ((const short8*)Vf)[(kc*2+1)*64 + lane], o1);
    }
#pragma unroll
    for(int r=0; r<4; ++r){
      size_t co = (size_t)(b*256 + st*16 + rg*4 + r)*96 + h*32;
      cat[co + c15]      = f2b(o0[r]);
      cat[co + 16 + c15] = f2b(o1[r]);
    }
  }
}

// ---------------------------------------------------------------------------
// kB: fused tail per (b, 64-row group) — grid 1024, 4 blocks/CU for wave
// overlap. mhp 2-GEMM + residual in registers, LN stats, mlp 4-GEMM chain,
// residual, out_W partial dot -> part[bid].
// ---------------------------------------------------------------------------
__global__ __launch_bounds__(256) void kB_tail(
    const unsigned short* __restrict__ cat, const float* __restrict__ xskip,
    const unsigned short* __restrict__ w1f, const float* __restrict__ b1,
    const unsigned short* __restrict__ w2f, const float* __restrict__ b2,
    const unsigned short* __restrict__ p1f, const float* __restrict__ p1b,
    const unsigned short* __restrict__ p2f, const float* __restrict__ pb2,
    const unsigned short* __restrict__ p3f, const float* __restrict__ pb3,
    const unsigned short* __restrict__ p4f, const float* __restrict__ pb4,
    const float* __restrict__ outw, float* __restrict__ part)
{
  __shared__ unsigned short catf[6144];
  __shared__ unsigned short fa[4096];
  __shared__ unsigned short fb[4096];
  __shared__ float rstat[4][64][2];
  __shared__ float red[4];
  const int tid = threadIdx.x, lane = tid&63, wv = tid>>6;
  const int c15 = lane&15, rg = lane>>4;
  const int bid = blockIdx.x, b = bid>>2, sg = bid&3;
  const unsigned short* cb = cat + (size_t)(b*256 + sg*64)*96;
#pragma unroll
  for(int it=0; it<24; ++it){
    int flat = it*256 + tid;
    int row = flat/96, col = flat - row*96;
    catf[ ((((row>>4)*3 + (col>>5))*64 + ((col&31)>>3)*16 + (row&15))<<3) + (col&7) ] = cb[flat];
  }
  __syncthreads();
  const short8* w1 = (const short8*)w1f;
  const short8* w2 = (const short8*)w2f;
  const short8* q1 = (const short8*)p1f;
  const short8* q2 = (const short8*)p2f;
  const short8* q3 = (const short8*)p3f;
  const short8* q4 = (const short8*)p4f;
  const int kch = wv>>1, gw = (wv&1)*2 + (c15>>3), jw = c15&7;
  {  // mhp G1 -> fa
    float bb = b1[wv*16+c15];
#pragma unroll
    for(int st=0; st<4; ++st){
      f32x4 a = {0.f,0.f,0.f,0.f};
#pragma unroll
      for(int kc=0; kc<3; ++kc)
        a = MFMA(*(const short8*)&catf[((st*3+kc)*64+lane)*8], w1[(kc*4+wv)*64+lane], a);
#pragma unroll
      for(int r=0; r<4; ++r)
        fa[ (((st*2+kch)*64 + gw*16 + rg*4 + r)<<3) + jw ] = f2b(a[r] + bb);
    }
  }
  __syncthreads();
  f32x4 xs2[4];
  const float* xr = xskip + (size_t)(b*256 + sg*64)*64;
  {  // mhp G2 + residual -> xs2 regs
    float bb = b2[wv*16+c15];
#pragma unroll
    for(int st=0; st<4; ++st){
      f32x4 a = {0.f,0.f,0.f,0.f};
#pragma unroll
      for(int kc=0; kc<2; ++kc)
        a = MFMA(*(const short8*)&fa[((st*2+kc)*64+lane)*8], w2[(kc*4+wv)*64+lane], a);
#pragma unroll
      for(int r=0; r<4; ++r)
        xs2[st][r] = a[r] + bb + xr[(st*16 + rg*4 + r)*64 + wv*16 + c15];
    }
  }
#pragma unroll
  for(int st=0; st<4; ++st)
#pragma unroll
    for(int r=0; r<4; ++r){
      float sv = xs2[st][r], qv = sv*sv;
      sv += __shfl_xor(sv,1); sv += __shfl_xor(sv,2); sv += __shfl_xor(sv,4); sv += __shfl_xor(sv,8);
      qv += __shfl_xor(qv,1); qv += __shfl_xor(qv,2); qv += __shfl_xor(qv,4); qv += __shfl_xor(qv,8);
      if(c15==0){ int row = st*16+rg*4+r; rstat[wv][row][0]=sv; rstat[wv][row][1]=qv; }
    }
  __syncthreads();
#pragma unroll
  for(int st=0; st<4; ++st)
#pragma unroll
    for(int r=0; r<4; ++r){
      int row = st*16+rg*4+r;
      float tsu = rstat[0][row][0]+rstat[1][row][0]+rstat[2][row][0]+rstat[3][row][0];
      float tqu = rstat[0][row][1]+rstat[1][row][1]+rstat[2][row][1]+rstat[3][row][1];
      float mean = tsu*(1.f/64.f);
      float rstd = rsqrtf(tqu*(1.f/64.f) - mean*mean + 1e-5f);
      fa[ (((st*2+kch)*64 + gw*16 + (row&15))<<3) + jw ] = f2b((xs2[st][r]-mean)*rstd);
    }
  __syncthreads();
  {  // mlp G1 (folded) -> fb
    float bb = p1b[wv*16+c15];
#pragma unroll
    for(int st=0; st<4; ++st){
      f32x4 a = {0.f,0.f,0.f,0.f};
#pragma unroll
      for(int kc=0; kc<2; ++kc)
        a = MFMA(*(const short8*)&fa[((st*2+kc)*64+lane)*8], q1[(kc*4+wv)*64+lane], a);
#pragma unroll
      for(int r=0; r<4; ++r)
        fb[ (((st*2+kch)*64 + gw*16 + rg*4 + r)<<3) + jw ] = f2b(a[r] + bb);
    }
  }
  __syncthreads();
  {  // mlp G2 + exact gelu -> fa
    float bb = pb2[wv*16+c15];
#pragma unroll
    for(int st=0; st<4; ++st){
      f32x4 a = {0.f,0.f,0.f,0.f};
#pragma unroll
      for(int kc=0; kc<2; ++kc)
        a = MFMA(*(const short8*)&fb[((st*2+kc)*64+lane)*8], q2[(kc*4+wv)*64+lane], a);
#pragma unroll
      for(int r=0; r<4; ++r){
        float v = a[r] + bb;
        v = 0.5f*v*(1.f + erff(v*0.70710678118654752440f));
        fa[ (((st*2+kch)*64 + gw*16 + rg*4 + r)<<3) + jw ] = f2b(v);
      }
    }
  }
  __syncthreads();
  {  // mlp G3 -> fb
    float bb = pb3[wv*16+c15];
#pragma unroll
    for(int st=0; st<4; ++st){
      f32x4 a = {0.f,0.f,0.f,0.f};
#pragma unroll
      for(int kc=0; kc<2; ++kc)
        a = MFMA(*(const short8*)&fa[((st*2+kc)*64+lane)*8], q3[(kc*4+wv)*64+lane], a);
#pragma unroll
      for(int r=0; r<4; ++r)
        fb[ (((st*2+kch)*64 + gw*16 + rg*4 + r)<<3) + jw ] = f2b(a[r] + bb);
    }
  }
  __syncthreads();
  {  // mlp G4 + residual + out_W partial dot
    float bb = pb4[wv*16+c15];
    float partial = 0.f;
#pragma unroll
    for(int st=0; st<4; ++st){
      f32x4 a = {0.f,0.f,0.f,0.f};
#pragma unroll
      for(int kc=0; kc<2; ++kc)
        a = MFMA(*(const short8*)&fb[((st*2+kc)*64+lane)*8], q4[(kc*4+wv)*64+lane], a);
#pragma unroll
      for(int r=0; r<4; ++r){
        int row = st*16 + rg*4 + r;
        float v = a[r] + bb + xs2[st][r];
        partial += v * outw[(sg*64 + row)*64 + wv*16 + c15];
      }
    }
    partial += __shfl_xor(partial,1); partial += __shfl_xor(partial,2);
    partial += __shfl_xor(partial,4); partial += __shfl_xor(partial,8);
    partial += __shfl_xor(partial,16); partial += __shfl_xor(partial,32);
    if(lane==0) red[wv] = partial;
    __syncthreads();
    if(tid==0) part[bid] = red[0]+red[1]+red[2]+red[3];
  }
}

__global__ void k5_out(const float* __restrict__ part, const float* __restrict__ outb,
                       float* __restrict__ out){
  int b = threadIdx.x;
  out[b] = part[b*4] + part[b*4+1] + part[b*4+2] + part[b*4+3] + outb[0];
}

// ---------------------------------------------------------------------------
extern "C" void kernel_launch(void* const* d_in, const int* in_sizes, int n_in,
                              void* d_out, int out_size, void* d_ws, size_t ws_size,
                              hipStream_t stream)
{
  const float* x    = (const float*)d_in[0];
  const float* ln1s = (const float*)d_in[1];
  const float* ln1b = (const float*)d_in[2];
  const float* inW  = (const float*)d_in[3];
  const float* inb  = (const float*)d_in[4];
  const float* ln2s = (const float*)d_in[5];
  const float* ln2b = (const float*)d_in[6];
  const float* mss  = (const float*)d_in[7];
  const float* msb  = (const float*)d_in[8];
  const float* Wq   = (const float*)d_in[9];
  const float* bq   = (const float*)d_in[10];
  const float* Wk   = (const float*)d_in[11];
  const float* bk   = (const float*)d_in[12];
  const float* Wv   = (const float*)d_in[13];
  const float* bv   = (const float*)d_in[14];
  const float* mhW1 = (const float*)d_in[15];
  const float* mhb1 = (const float*)d_in[16];
  const float* mhW2 = (const float*)d_in[17];
  const float* mhb2 = (const float*)d_in[18];
  const float* mls  = (const float*)d_in[19];
  const float* mlb  = (const float*)d_in[20];
  const float* mW1  = (const float*)d_in[21];
  const float* mb1  = (const float*)d_in[22];
  const float* mW2  = (const float*)d_in[23];
  const float* mb2  = (const float*)d_in[24];
  const float* mW3  = (const float*)d_in[25];
  const float* mb3  = (const float*)d_in[26];
  const float* mW4  = (const float*)d_in[27];
  const float* mb4  = (const float*)d_in[28];
  const float* outW = (const float*)d_in[29];
  const float* outb = (const float*)d_in[30];
  (void)in_sizes; (void)n_in; (void)out_size;

  // workspace layout (bytes)
  char* ws = (char*)d_ws;
  float*          xskip    = (float*)         (ws + 0);          // 16,777,216
  unsigned short* cat      = (unsigned short*)(ws + 16777216);   // 12,582,912
  unsigned short* wsw      = (unsigned short*)(ws + 29360128);   //    188,416
  float*          rowstats = (float*)         (ws + 29548544);   //    524,288
  float*          qkvb     = (float*)         (ws + 30072832);   //      1,152
  float*          mlpb1    = (float*)         (ws + 30073984);   //        256
  float*          part     = (float*)         (ws + 30074240);   //      4,096
  if(ws_size < 30078336u) return;

  float* out = (float*)d_out;

  kprep<<<dim3(192), dim3(256), 0, stream>>>(inW, wsw);
  k1_patch<<<dim3(4096 + 178), dim3(256), 0, stream>>>(x, ln1s, ln1b, wsw, inb,
      ln2s, ln2b, xskip, rowstats,
      inW, Wq, Wk, Wv, mhW1, mhW2, mW1, mW2, mW3, mW4,
      mss, mls, msb, bq, bk, bv, mlb, mb1, qkvb, mlpb1);
  kA_attn<<<dim3(768), dim3(256), 0, stream>>>(xskip, rowstats, wsw, qkvb, cat);
  kB_tail<<<dim3(1024), dim3(256), 0, stream>>>(cat, xskip,
      wsw + 67584, mhb1, wsw + 73728, mhb2,
      wsw + 77824, mlpb1, wsw + 81920, mb2, wsw + 86016, mb3, wsw + 90112, mb4,
      outW, part);
  k5_out<<<dim3(1), dim3(256), 0, stream>>>(part, outb, out);
}

// Round 6
// 114.273 us; speedup vs baseline: 1.2359x; 1.1132x over previous
//
#include <hip/hip_runtime.h>
#include <math.h>

typedef __attribute__((ext_vector_type(8))) short short8;
typedef __attribute__((ext_vector_type(4))) short short4v;
typedef __attribute__((ext_vector_type(4))) float f32x4;
typedef __attribute__((ext_vector_type(2))) float f32x2;

#define DEV static __device__ __forceinline__

DEV unsigned short f2b(float f){            // fp32 -> bf16 (RNE)
  union{float f; unsigned u;} x; x.f = f;
  unsigned r = (x.u + 0x7fffu + ((x.u>>16)&1u))>>16;
  return (unsigned short)r;
}

#define MFMA(a,b,c) __builtin_amdgcn_mfma_f32_16x16x32_bf16((a),(b),(c),0,0,0)

// ---------------------------------------------------------------------------
// Weight-prep: ids [0,94208) -> bf16 B-frag order (LN-affine folded);
// [94208,94496) qkv bias folds; [94496,94560) mlp b1 fold.
// ---------------------------------------------------------------------------
DEV void prep_one(int id,
    const float* inW, const float* Wq, const float* Wk, const float* Wv,
    const float* m1, const float* m2,
    const float* p1, const float* p2, const float* p3, const float* p4,
    const float* mss, const float* mls, const float* msb,
    const float* bq, const float* bk, const float* bv,
    const float* mlb, const float* mb1,
    unsigned short* wsw, float* qkvb, float* mlpb1)
{
  if(id < 94208){
    const float* src; int NT, base; int harg = -1, w1flag = 0;
    if      (id < 49152){ src=inW; NT=4; base=0; }
    else if (id < 67584){ int r=id-49152; int slab=r>>11; int h=slab/3, m=slab-h*3;
                          src=(m==0?Wq:(m==1?Wk:Wv))+h*2048; NT=2; base=49152+slab*2048; harg=h; }
    else if (id < 73728){ src=m1; NT=4; base=67584; }
    else if (id < 77824){ src=m2; NT=4; base=73728; }
    else if (id < 81920){ src=p1; NT=4; base=77824; w1flag=1; }
    else if (id < 86016){ src=p2; NT=4; base=81920; }
    else if (id < 90112){ src=p3; NT=4; base=86016; }
    else                { src=p4; NT=4; base=90112; }
    int o = id - base;
    int j = o&7, l = (o>>3)&63, rest = o>>9;
    int nt = rest % NT, kc = rest / NT;
    int k = kc*32 + ((l>>4)<<3) + j;
    int n = nt*16 + (l&15);
    float scale = 1.f;
    if(harg >= 0) scale = mss[harg*64 + k];
    if(w1flag)    scale = mls[k];
    wsw[id] = f2b(src[k*(NT*16) + n] * scale);
  } else if(id < 94496){
    int o = id - 94208;                     // 288: h*96 + m*32 + e
    int h = o/96, m = (o - h*96)/32, e = o&31;
    const float* W  = (m==0?Wq:(m==1?Wk:Wv)) + h*2048;
    const float* bb = (m==0?bq:(m==1?bk:bv));
    float s = 0.f;
    for(int l=0;l<64;++l) s += msb[h*64+l]*W[l*32+e];
    qkvb[o] = s + bb[h*32+e];
  } else if(id < 94560){
    int n = id - 94496;
    float s = 0.f;
    for(int l=0;l<64;++l) s += mlb[l]*p1[l*64+n];
    mlpb1[n] = s + mb1[n];
  }
}

// kprep: only the in_W frags (needed by k1). 192 blocks.
__global__ __launch_bounds__(256) void kprep(
    const float* __restrict__ inW, unsigned short* __restrict__ wsw)
{
  int id = blockIdx.x*256 + threadIdx.x;   // < 49152
  int o = id;
  int j = o&7, l = (o>>3)&63, rest = o>>9;
  int nt = rest & 3, kc = rest >> 2;
  int k = kc*32 + ((l>>4)<<3) + j;
  int n = nt*16 + (l&15);
  wsw[id] = f2b(inW[k*64 + n]);
}

// ---------------------------------------------------------------------------
// k1: blocks <4096: patchify + LN(768) + GEMM(768->64) + bias + LN(64)
//     -> xskip (f32) + z (bf16, kA A-frag order). Blocks >=4096: weight prep.
// A-frag flat index for z[rl][col] (rl,col in 256x64 per b):
//   f = ((rl>>4)*2 + (col>>5))*512 + ((col&31)>>3)*128 + (rl&15)*8 + (col&7)
// ---------------------------------------------------------------------------
__global__ __launch_bounds__(256) void k1_patch(
    const float* __restrict__ x,
    const float* __restrict__ ln1s, const float* __restrict__ ln1b,
    unsigned short* __restrict__ wsw, const float* __restrict__ inb,
    const float* __restrict__ ln2s, const float* __restrict__ ln2b,
    float* __restrict__ xskip, unsigned short* __restrict__ zf,
    const float* __restrict__ inW,
    const float* __restrict__ Wq, const float* __restrict__ Wk,
    const float* __restrict__ Wv,
    const float* __restrict__ m1, const float* __restrict__ m2,
    const float* __restrict__ p1, const float* __restrict__ p2,
    const float* __restrict__ p3, const float* __restrict__ p4,
    const float* __restrict__ mss, const float* __restrict__ mls,
    const float* __restrict__ msb,
    const float* __restrict__ bq, const float* __restrict__ bk,
    const float* __restrict__ bv,
    const float* __restrict__ mlb, const float* __restrict__ mb1,
    float* __restrict__ qkvb, float* __restrict__ mlpb1)
{
  const int tid = threadIdx.x;
  const int bp = blockIdx.x;
  if(bp >= 4096){
    int id = 49152 + (bp - 4096)*256 + tid;
    prep_one(id, inW, Wq, Wk, Wv, m1, m2, p1, p2, p3, p4,
             mss, mls, msb, bq, bk, bv, mlb, mb1, wsw, qkvb, mlpb1);
    return;
  }
  __shared__ unsigned short Tf[24*64*8];
  __shared__ float Cbuf[16][68];
  __shared__ float wstat[4][16][2];
  const int lane = tid & 63, wv = tid >> 6;
  const int p1i = tid & 15, jj = tid >> 4;
  const int b = bp >> 4, p0 = bp & 15;

  const float* xb = x + (size_t)b * (3*256*256);
  float rv[48]; float sum=0.f, ssq=0.f;
#pragma unroll
  for(int rr=0; rr<48; ++rr){
    int c = rr >> 4, i = rr & 15;
    float v = xb[(c*256 + i*16 + p0)*256 + tid];
    rv[rr] = v; sum += v; ssq += v*v;
  }
  sum += __shfl_xor(sum, 16); sum += __shfl_xor(sum, 32);
  ssq += __shfl_xor(ssq, 16); ssq += __shfl_xor(ssq, 32);
  if(lane < 16){ wstat[wv][lane][0] = sum; wstat[wv][lane][1] = ssq; }
  __syncthreads();
  float ts = wstat[0][p1i][0] + wstat[1][p1i][0] + wstat[2][p1i][0] + wstat[3][p1i][0];
  float tq = wstat[0][p1i][1] + wstat[1][p1i][1] + wstat[2][p1i][1] + wstat[3][p1i][1];
  float mean = ts * (1.f/768.f);
  float var  = tq * (1.f/768.f) - mean*mean;
  float rstd = rsqrtf(var + 1e-5f);
#pragma unroll
  for(int rr=0; rr<48; ++rr){
    int c = rr >> 4, i = rr & 15;
    int d = c*256 + i*16 + jj;
    float xv = (rv[rr]-mean)*rstd*ln1s[d] + ln1b[d];
    int g = (((i&1)<<4) + jj) >> 3;
    Tf[ (((d>>5)*64 + g*16 + p1i)<<3) + (jj&7) ] = f2b(xv);
  }
  __syncthreads();

  f32x4 acc = {0.f,0.f,0.f,0.f};
  const short8* wf = (const short8*)wsw;
#pragma unroll
  for(int kc=0; kc<24; ++kc){
    short8 a  = *(const short8*)&Tf[(kc*64 + lane)*8];
    short8 bb = wf[(kc*4 + wv)*64 + lane];
    acc = MFMA(a, bb, acc);
  }
  const int c15 = lane & 15, rg = lane >> 4;
  float bias = inb[wv*16 + c15];
#pragma unroll
  for(int r=0; r<4; ++r) Cbuf[rg*4+r][wv*16+c15] = acc[r] + bias;
  __syncthreads();

  {
    int row = tid >> 4, cq = (tid & 15) * 4;
    float v0=Cbuf[row][cq+0], v1=Cbuf[row][cq+1], v2=Cbuf[row][cq+2], v3=Cbuf[row][cq+3];
    float s = v0+v1+v2+v3;
    float q = v0*v0+v1*v1+v2*v2+v3*v3;
    s += __shfl_xor(s,1); s += __shfl_xor(s,2); s += __shfl_xor(s,4); s += __shfl_xor(s,8);
    q += __shfl_xor(q,1); q += __shfl_xor(q,2); q += __shfl_xor(q,4); q += __shfl_xor(q,8);
    float m2  = s*(1.f/64.f);
    float rs2 = rsqrtf(q*(1.f/64.f) - m2*m2 + 1e-5f);
    f32x4 o;
    o[0] = (v0-m2)*rs2*ln2s[cq+0] + ln2b[cq+0];
    o[1] = (v1-m2)*rs2*ln2s[cq+1] + ln2b[cq+1];
    o[2] = (v2-m2)*rs2*ln2s[cq+2] + ln2b[cq+2];
    o[3] = (v3-m2)*rs2*ln2s[cq+3] + ln2b[cq+3];
    int grow = b*256 + p0*16 + row;
    *(f32x4*)&xskip[ (size_t)grow*64 + cq ] = o;
    // second LN stats (all 16 lanes get totals via butterfly)
    float s2 = o[0]+o[1]+o[2]+o[3];
    float q2 = o[0]*o[0]+o[1]*o[1]+o[2]*o[2]+o[3]*o[3];
    s2 += __shfl_xor(s2,1); s2 += __shfl_xor(s2,2); s2 += __shfl_xor(s2,4); s2 += __shfl_xor(s2,8);
    q2 += __shfl_xor(q2,1); q2 += __shfl_xor(q2,2); q2 += __shfl_xor(q2,4); q2 += __shfl_xor(q2,8);
    float mm  = s2*(1.f/64.f);
    float rr2 = rsqrtf(q2*(1.f/64.f) - mm*mm + 1e-5f);
    short4v zz;
    zz[0] = (short)f2b((o[0]-mm)*rr2);
    zz[1] = (short)f2b((o[1]-mm)*rr2);
    zz[2] = (short)f2b((o[2]-mm)*rr2);
    zz[3] = (short)f2b((o[3]-mm)*rr2);
    int fi = (p0*2 + (cq>>5))*512 + ((cq&31)>>3)*128 + row*8 + (cq&7);
    *(short4v*)&zf[ (size_t)b*16384 + fi ] = zz;
  }
}

// ---------------------------------------------------------------------------
// kA: fused attention per (b,h). A-frags (z) loaded DIRECTLY from global in
// frag order (coalesced 16B/lane); QKV MFMAs -> Q in regs (per-wave scratch
// readback), K,V in LDS; QK^T, in-register softmax, P staged per-kc through
// per-wave scratch, PV -> cat. 40 KB LDS -> 4 blocks/CU.
// ---------------------------------------------------------------------------
__global__ __launch_bounds__(256) void kA_attn(
    const unsigned short* __restrict__ zf,
    const unsigned short* __restrict__ wsw, const float* __restrict__ qkvb,
    unsigned short* __restrict__ cat)
{
  __shared__ unsigned short Kf[8192];      // 16 KB
  __shared__ unsigned short Vf[8192];      // 16 KB
  __shared__ unsigned short scr[4][1024];  //  8 KB (per-wave 2 KB)
  const int tid = threadIdx.x, lane = tid&63, wv = tid>>6;
  const int c15 = lane&15, rg = lane>>4;
  const int id = blockIdx.x, b = id/3, h = id - b*3;
  const short8* zg = (const short8*)(zf + (size_t)b*16384);
  const short8* wf = ((const short8*)(wsw + 49152)) + h*3*256;
  unsigned short* sw = scr[wv];
  float be[6];
#pragma unroll
  for(int i=0;i<6;++i) be[i] = qkvb[(h*3 + (i>>1))*32 + (i&1)*16 + c15];

  short8 aq[4];                            // Q A-frags, one per st
#pragma unroll
  for(int si=0; si<4; ++si){
    const int st = wv + si*4;
    short8 a0 = zg[(st*2+0)*64 + lane];
    short8 a1 = zg[(st*2+1)*64 + lane];
#pragma unroll
    for(int mat=0; mat<3; ++mat){
#pragma unroll
      for(int et=0; et<2; ++et){
        f32x4 acc = {0.f,0.f,0.f,0.f};
        acc = MFMA(a0, wf[mat*256 + et*64 + lane], acc);
        acc = MFMA(a1, wf[mat*256 + (2+et)*64 + lane], acc);
        float bias = be[mat*2+et];
#pragma unroll
        for(int r=0;r<4;++r){
          unsigned short val = f2b(acc[r] + bias);
          int s15 = rg*4 + r;
          if(mat==0){
            sw[ ((et*2 + (c15>>3))*16 + s15)*8 + (c15&7) ] = val;
          } else if(mat==1){
            Kf[ (st*64 + (et*2 + (c15>>3))*16 + s15)*8 + (c15&7) ] = val;
          } else {
            int s = st*16 + s15;
            Vf[ (((s>>5)*2 + et)*64 + ((s&31)>>3)*16 + c15)*8 + (s&7) ] = val;
          }
        }
      }
      if(mat==0) aq[si] = ((const short8*)sw)[lane];   // wave-local readback
    }
  }
  __syncthreads();

  const f32x4 z4 = {0.f,0.f,0.f,0.f};
#pragma unroll
  for(int si=0; si<4; ++si){
    const int st = wv + si*4;
    f32x4 sc[16];
#pragma unroll
    for(int tt=0; tt<16; ++tt) sc[tt] = MFMA(aq[si], ((const short8*)Kf)[tt*64 + lane], z4);
    float mx[4], sm[4];
#pragma unroll
    for(int r=0; r<4; ++r){
      float m = sc[0][r];
#pragma unroll
      for(int tt=1; tt<16; ++tt) m = fmaxf(m, sc[tt][r]);
      m = fmaxf(m, __shfl_xor(m,1)); m = fmaxf(m, __shfl_xor(m,2));
      m = fmaxf(m, __shfl_xor(m,4)); m = fmaxf(m, __shfl_xor(m,8));
      mx[r] = m; sm[r] = 0.f;
    }
#pragma unroll
    for(int tt=0; tt<16; ++tt)
#pragma unroll
      for(int r=0; r<4; ++r){
        float e = __expf(sc[tt][r] - mx[r]);
        sc[tt][r] = e; sm[r] += e;
      }
#pragma unroll
    for(int r=0; r<4; ++r){
      float s = sm[r];
      s += __shfl_xor(s,1); s += __shfl_xor(s,2); s += __shfl_xor(s,4); s += __shfl_xor(s,8);
      sm[r] = 1.f / s;
    }
    f32x4 o0 = z4, o1 = z4;
#pragma unroll
    for(int kc=0; kc<8; ++kc){
#pragma unroll
      for(int t2=0; t2<2; ++t2){
        int tt = kc*2 + t2;
        int tbr = t2*16 + c15;
#pragma unroll
        for(int r=0; r<4; ++r)
          sw[ (((tbr>>3)*16 + rg*4 + r)<<3) + (tbr&7) ] = f2b(sc[tt][r] * sm[r]);
      }
      short8 pa = ((const short8*)sw)[lane];
      o0 = MFMA(pa, ((const short8*)Vf)[(kc*2+0)*64 + lane], o0);
      o1 = MFMA(pa, ((const short8*)Vf)[(kc*2+1)*64 + lane], o1);
    }
#pragma unroll
    for(int r=0; r<4; ++r){
      size_t co = (size_t)(b*256 + st*16 + rg*4 + r)*96 + h*32;
      cat[co + c15]      = f2b(o0[r]);
      cat[co + 16 + c15] = f2b(o1[r]);
    }
  }
}

// ---------------------------------------------------------------------------
// kB: fused tail per (b, 64-row group) — grid 1024, 4 blocks/CU. mhp 2-GEMM
// + residual in regs, LN stats, mlp 4-GEMM chain, residual, out_W dot.
// ---------------------------------------------------------------------------
__global__ __launch_bounds__(256) void kB_tail(
    const unsigned short* __restrict__ cat, const float* __restrict__ xskip,
    const unsigned short* __restrict__ w1f, const float* __restrict__ b1,
    const unsigned short* __restrict__ w2f, const float* __restrict__ b2,
    const unsigned short* __restrict__ p1f, const float* __restrict__ p1b,
    const unsigned short* __restrict__ p2f, const float* __restrict__ pb2,
    const unsigned short* __restrict__ p3f, const float* __restrict__ pb3,
    const unsigned short* __restrict__ p4f, const float* __restrict__ pb4,
    const float* __restrict__ outw, float* __restrict__ part)
{
  __shared__ unsigned short catf[6144];
  __shared__ unsigned short fa[4096];
  __shared__ unsigned short fb[4096];
  __shared__ float rstat[4][64][2];
  __shared__ float red[4];
  const int tid = threadIdx.x, lane = tid&63, wv = tid>>6;
  const int c15 = lane&15, rg = lane>>4;
  const int bid = blockIdx.x, b = bid>>2, sg = bid&3;
  const unsigned short* cb = cat + (size_t)(b*256 + sg*64)*96;
#pragma unroll
  for(int it=0; it<24; ++it){
    int flat = it*256 + tid;
    int row = flat/96, col = flat - row*96;
    catf[ ((((row>>4)*3 + (col>>5))*64 + ((col&31)>>3)*16 + (row&15))<<3) + (col&7) ] = cb[flat];
  }
  __syncthreads();
  const short8* w1 = (const short8*)w1f;
  const short8* w2 = (const short8*)w2f;
  const short8* q1 = (const short8*)p1f;
  const short8* q2 = (const short8*)p2f;
  const short8* q3 = (const short8*)p3f;
  const short8* q4 = (const short8*)p4f;
  const int kch = wv>>1, gw = (wv&1)*2 + (c15>>3), jw = c15&7;
  {  // mhp G1 -> fa
    float bb = b1[wv*16+c15];
#pragma unroll
    for(int st=0; st<4; ++st){
      f32x4 a = {0.f,0.f,0.f,0.f};
#pragma unroll
      for(int kc=0; kc<3; ++kc)
        a = MFMA(*(const short8*)&catf[((st*3+kc)*64+lane)*8], w1[(kc*4+wv)*64+lane], a);
#pragma unroll
      for(int r=0; r<4; ++r)
        fa[ (((st*2+kch)*64 + gw*16 + rg*4 + r)<<3) + jw ] = f2b(a[r] + bb);
    }
  }
  __syncthreads();
  f32x4 xs2[4];
  const float* xr = xskip + (size_t)(b*256 + sg*64)*64;
  {  // mhp G2 + residual -> xs2 regs
    float bb = b2[wv*16+c15];
#pragma unroll
    for(int st=0; st<4; ++st){
      f32x4 a = {0.f,0.f,0.f,0.f};
#pragma unroll
      for(int kc=0; kc<2; ++kc)
        a = MFMA(*(const short8*)&fa[((st*2+kc)*64+lane)*8], w2[(kc*4+wv)*64+lane], a);
#pragma unroll
      for(int r=0; r<4; ++r)
        xs2[st][r] = a[r] + bb + xr[(st*16 + rg*4 + r)*64 + wv*16 + c15];
    }
  }
#pragma unroll
  for(int st=0; st<4; ++st)
#pragma unroll
    for(int r=0; r<4; ++r){
      float sv = xs2[st][r], qv = sv*sv;
      sv += __shfl_xor(sv,1); sv += __shfl_xor(sv,2); sv += __shfl_xor(sv,4); sv += __shfl_xor(sv,8);
      qv += __shfl_xor(qv,1); qv += __shfl_xor(qv,2); qv += __shfl_xor(qv,4); qv += __shfl_xor(qv,8);
      if(c15==0){ int row = st*16+rg*4+r; rstat[wv][row][0]=sv; rstat[wv][row][1]=qv; }
    }
  __syncthreads();
#pragma unroll
  for(int st=0; st<4; ++st)
#pragma unroll
    for(int r=0; r<4; ++r){
      int row = st*16+rg*4+r;
      float tsu = rstat[0][row][0]+rstat[1][row][0]+rstat[2][row][0]+rstat[3][row][0];
      float tqu = rstat[0][row][1]+rstat[1][row][1]+rstat[2][row][1]+rstat[3][row][1];
      float mean = tsu*(1.f/64.f);
      float rstd = rsqrtf(tqu*(1.f/64.f) - mean*mean + 1e-5f);
      fa[ (((st*2+kch)*64 + gw*16 + (row&15))<<3) + jw ] = f2b((xs2[st][r]-mean)*rstd);
    }
  __syncthreads();
  {  // mlp G1 (folded) -> fb
    float bb = p1b[wv*16+c15];
#pragma unroll
    for(int st=0; st<4; ++st){
      f32x4 a = {0.f,0.f,0.f,0.f};
#pragma unroll
      for(int kc=0; kc<2; ++kc)
        a = MFMA(*(const short8*)&fa[((st*2+kc)*64+lane)*8], q1[(kc*4+wv)*64+lane], a);
#pragma unroll
      for(int r=0; r<4; ++r)
        fb[ (((st*2+kch)*64 + gw*16 + rg*4 + r)<<3) + jw ] = f2b(a[r] + bb);
    }
  }
  __syncthreads();
  {  // mlp G2 + exact gelu -> fa
    float bb = pb2[wv*16+c15];
#pragma unroll
    for(int st=0; st<4; ++st){
      f32x4 a = {0.f,0.f,0.f,0.f};
#pragma unroll
      for(int kc=0; kc<2; ++kc)
        a = MFMA(*(const short8*)&fb[((st*2+kc)*64+lane)*8], q2[(kc*4+wv)*64+lane], a);
#pragma unroll
      for(int r=0; r<4; ++r){
        float v = a[r] + bb;
        v = 0.5f*v*(1.f + erff(v*0.70710678118654752440f));
        fa[ (((st*2+kch)*64 + gw*16 + rg*4 + r)<<3) + jw ] = f2b(v);
      }
    }
  }
  __syncthreads();
  {  // mlp G3 -> fb
    float bb = pb3[wv*16+c15];
#pragma unroll
    for(int st=0; st<4; ++st){
      f32x4 a = {0.f,0.f,0.f,0.f};
#pragma unroll
      for(int kc=0; kc<2; ++kc)
        a = MFMA(*(const short8*)&fa[((st*2+kc)*64+lane)*8], q3[(kc*4+wv)*64+lane], a);
#pragma unroll
      for(int r=0; r<4; ++r)
        fb[ (((st*2+kch)*64 + gw*16 + rg*4 + r)<<3) + jw ] = f2b(a[r] + bb);
    }
  }
  __syncthreads();
  {  // mlp G4 + residual + out_W partial dot
    float bb = pb4[wv*16+c15];
    float partial = 0.f;
#pragma unroll
    for(int st=0; st<4; ++st){
      f32x4 a = {0.f,0.f,0.f,0.f};
#pragma unroll
      for(int kc=0; kc<2; ++kc)
        a = MFMA(*(const short8*)&fb[((st*2+kc)*64+lane)*8], q4[(kc*4+wv)*64+lane], a);
#pragma unroll
      for(int r=0; r<4; ++r){
        int row = st*16 + rg*4 + r;
        float v = a[r] + bb + xs2[st][r];
        partial += v * outw[(sg*64 + row)*64 + wv*16 + c15];
      }
    }
    partial += __shfl_xor(partial,1); partial += __shfl_xor(partial,2);
    partial += __shfl_xor(partial,4); partial += __shfl_xor(partial,8);
    partial += __shfl_xor(partial,16); partial += __shfl_xor(partial,32);
    if(lane==0) red[wv] = partial;
    __syncthreads();
    if(tid==0) part[bid] = red[0]+red[1]+red[2]+red[3];
  }
}

__global__ void k5_out(const float* __restrict__ part, const float* __restrict__ outb,
                       float* __restrict__ out){
  int b = threadIdx.x;
  out[b] = part[b*4] + part[b*4+1] + part[b*4+2] + part[b*4+3] + outb[0];
}

// ---------------------------------------------------------------------------
extern "C" void kernel_launch(void* const* d_in, const int* in_sizes, int n_in,
                              void* d_out, int out_size, void* d_ws, size_t ws_size,
                              hipStream_t stream)
{
  const float* x    = (const float*)d_in[0];
  const float* ln1s = (const float*)d_in[1];
  const float* ln1b = (const float*)d_in[2];
  const float* inW  = (const float*)d_in[3];
  const float* inb  = (const float*)d_in[4];
  const float* ln2s = (const float*)d_in[5];
  const float* ln2b = (const float*)d_in[6];
  const float* mss  = (const float*)d_in[7];
  const float* msb  = (const float*)d_in[8];
  const float* Wq   = (const float*)d_in[9];
  const float* bq   = (const float*)d_in[10];
  const float* Wk   = (const float*)d_in[11];
  const float* bk   = (const float*)d_in[12];
  const float* Wv   = (const float*)d_in[13];
  const float* bv   = (const float*)d_in[14];
  const float* mhW1 = (const float*)d_in[15];
  const float* mhb1 = (const float*)d_in[16];
  const float* mhW2 = (const float*)d_in[17];
  const float* mhb2 = (const float*)d_in[18];
  const float* mls  = (const float*)d_in[19];
  const float* mlb  = (const float*)d_in[20];
  const float* mW1  = (const float*)d_in[21];
  const float* mb1  = (const float*)d_in[22];
  const float* mW2  = (const float*)d_in[23];
  const float* mb2  = (const float*)d_in[24];
  const float* mW3  = (const float*)d_in[25];
  const float* mb3  = (const float*)d_in[26];
  const float* mW4  = (const float*)d_in[27];
  const float* mb4  = (const float*)d_in[28];
  const float* outW = (const float*)d_in[29];
  const float* outb = (const float*)d_in[30];
  (void)in_sizes; (void)n_in; (void)out_size;

  // workspace layout (bytes)
  char* ws = (char*)d_ws;
  float*          xskip = (float*)         (ws + 0);          // 16,777,216
  unsigned short* cat   = (unsigned short*)(ws + 16777216);   // 12,582,912
  unsigned short* wsw   = (unsigned short*)(ws + 29360128);   //    188,416
  unsigned short* zf    = (unsigned short*)(ws + 29548544);   //  8,388,608
  float*          qkvb  = (float*)         (ws + 37937152);   //      1,152
  float*          mlpb1 = (float*)         (ws + 37938304);   //        256
  float*          part  = (float*)         (ws + 37938560);   //      4,096
  if(ws_size < 37942656u) return;

  float* out = (float*)d_out;

  kprep<<<dim3(192), dim3(256), 0, stream>>>(inW, wsw);
  k1_patch<<<dim3(4096 + 178), dim3(256), 0, stream>>>(x, ln1s, ln1b, wsw, inb,
      ln2s, ln2b, xskip, zf,
      inW, Wq, Wk, Wv, mhW1, mhW2, mW1, mW2, mW3, mW4,
      mss, mls, msb, bq, bk, bv, mlb, mb1, qkvb, mlpb1);
  kA_attn<<<dim3(768), dim3(256), 0, stream>>>(zf, wsw, qkvb, cat);
  kB_tail<<<dim3(1024), dim3(256), 0, stream>>>(cat, xskip,
      wsw + 67584, mhb1, wsw + 73728, mhb2,
      wsw + 77824, mlpb1, wsw + 81920, mb2, wsw + 86016, mb3, wsw + 90112, mb4,
      outW, part);
  k5_out<<<dim3(1), dim3(256), 0, stream>>>(part, outb, out);
}